// Round 7
// baseline (398.914 us; speedup 1.0000x reference)
//
#include <hip/hip_runtime.h>
#include <hip/hip_bf16.h>
#include <stdint.h>

// CrossAttnBlock: out = softmax((x Wq^T)(cond Wk^T)^T / 8) (cond Wv^T) Wo^T
// B=16 Lq=4096 Lk=77 D=512 Dc=768 H=8 Hd=64.
//
// R11 = R10 resubmit (round-6 failure was container acquisition; same infra
// signature as rounds 0/4, both of which passed unchanged on resubmit).
// gemm_bt: 2-phase double-buffered pipeline (T3-minimum + T14): LDS x2
// (64KB), ONE barrier/K-step; next-tile B staged via global_load_lds issued
// before the MFMA cluster; next-tile fp32 A prefetched to regs before MFMA,
// cvt+ds_write after MFMA. prep and attn_fused unchanged (controls).

typedef __bf16 bf16_t;
typedef __bf16 bf16x8 __attribute__((ext_vector_type(8)));
typedef float floatx4 __attribute__((ext_vector_type(4)));

#define MFMA16(a, b, c) __builtin_amdgcn_mfma_f32_16x16x32_bf16((a), (b), (c), 0, 0, 0)

__device__ __forceinline__ void gload_lds16(const bf16_t* g, bf16_t* l)
{
    __builtin_amdgcn_global_load_lds(
        (const __attribute__((address_space(1))) void*)g,
        (__attribute__((address_space(3))) void*)l, 16, 0, 0);
}

// load 8 fp32, convert, store bf16x8 (register-staged LDS write)
__device__ __forceinline__ void stage_cvt8(const float* g, bf16_t* l)
{
    floatx4 f0 = *(const floatx4*)g;
    floatx4 f1 = *(const floatx4*)(g + 4);
    bf16x8 v;
#pragma unroll
    for (int e = 0; e < 4; e++) { v[e] = (bf16_t)f0[e]; v[e + 4] = (bf16_t)f1[e]; }
    *(bf16x8*)l = v;
}

__device__ __forceinline__ void cvt8(const float* in, bf16_t* out, long long i)
{
    floatx4 f0 = *(const floatx4*)(in + i * 8);
    floatx4 f1 = *(const floatx4*)(in + i * 8 + 4);
    bf16x8 v;
#pragma unroll
    for (int e = 0; e < 4; e++) { v[e] = (bf16_t)f0[e]; v[e + 4] = (bf16_t)f1[e]; }
    *(bf16x8*)(out + i * 8) = v;
}

// ---------------------------------------------------------------------------
// C[M,N] = A[M,K] @ B[N,K]^T
// AF32: A fp32 (reg-prefetch + cvt + ds_write); else bf16 via global_load_lds.
// B always bf16 via global_load_lds. CF32 selects output dtype.
// 128x128 tile, BK=64 ([2][128][32] kk-split per buffer), DOUBLE-buffered LDS,
// one barrier per K-step. XCD-chunked swizzle. K%64==0.
// grid: (N/128, M/128), block 256 (4 waves, 2x2).
// ---------------------------------------------------------------------------
#define TSZ (2 * 128 * 32)   // elems per buffer per matrix

template <bool AF32, bool CF32>
__global__ __launch_bounds__(256) void gemm_bt(
    const void* __restrict__ Av, const bf16_t* __restrict__ B,
    void* __restrict__ Cv, int M, int N, int K)
{
    __shared__ bf16_t As[2 * TSZ];   // [buf][kk][row][col0..31], 32 KB
    __shared__ bf16_t Bs[2 * TSZ];

    const int t = threadIdx.x;
    const int l = t & 63;
    const int w = t >> 6;
    const int wm = w >> 1, wn = w & 1;
    const int l15 = l & 15, l4 = l >> 4;

    // XCD-chunked swizzle (bijective; our launches have nwg%8==0)
    const int nbx = gridDim.x;
    const int nwg = nbx * gridDim.y;
    int lid = blockIdx.y * nbx + blockIdx.x;
    if ((nwg & 7) == 0) {
        const int cpx = nwg >> 3;
        lid = (lid & 7) * cpx + (lid >> 3);
    }
    const int m0 = (lid / nbx) * 128, n0 = (lid % nbx) * 128;

    floatx4 acc[4][4] = {};

    // staging geometry: 256 threads x 4 chunks x 8 elems = full [2][128][32].
    const float*  agf[4];
    const bf16_t* agb[4];
    const bf16_t* bg[4];
    int eo[4];                        // elem offset within one buffer
#pragma unroll
    for (int i = 0; i < 4; i++) {
        int e = (i * 256 + t) * 8;
        int kk = e >> 12;
        int row = (e & 4095) >> 5;
        int col = kk * 32 + (e & 31);
        int ra = m0 + row; if (ra > M - 1) ra = M - 1;
        if (AF32) agf[i] = (const float*)Av + (size_t)ra * K + col;
        else      agb[i] = (const bf16_t*)Av + (size_t)ra * K + col;
        bg[i] = B + (size_t)(n0 + row) * K + col;
        eo[i] = e;
    }

    // --- prologue: stage tile 0 into buffer 0 ---
#pragma unroll
    for (int i = 0; i < 4; i++) {
        if (AF32) stage_cvt8(agf[i], &As[eo[i]]);
        else      gload_lds16(agb[i], &As[eo[i]]);
        gload_lds16(bg[i], &Bs[eo[i]]);
    }
    __syncthreads();

    const int nt = K >> 6;
    int cur = 0;
    for (int tt = 0; tt < nt; ++tt) {
        const int kn = (tt + 1) << 6;
        const int nxt = (cur ^ 1) * TSZ;
        const bool more = (tt + 1 < nt);

        // 1. issue next-tile loads FIRST (latency overlaps ds_read + MFMA)
        floatx4 pf0[4], pf1[4];
        if (more) {
            if (AF32) {
#pragma unroll
                for (int i = 0; i < 4; i++) {
                    pf0[i] = *(const floatx4*)(agf[i] + kn);
                    pf1[i] = *(const floatx4*)(agf[i] + kn + 4);
                }
            } else {
#pragma unroll
                for (int i = 0; i < 4; i++)
                    gload_lds16(agb[i] + kn, &As[nxt + eo[i]]);
            }
#pragma unroll
            for (int i = 0; i < 4; i++)
                gload_lds16(bg[i] + kn, &Bs[nxt + eo[i]]);
        }

        // 2. ds_read current-tile fragments
        const int cb = cur * TSZ;
        bf16x8 af[2][4], bfr[2][4];
#pragma unroll
        for (int kk = 0; kk < 2; kk++) {
#pragma unroll
            for (int i = 0; i < 4; i++) {
                af[kk][i]  = *(const bf16x8*)&As[cb + kk * 4096 + (wm * 64 + i * 16 + l15) * 32 + l4 * 8];
                bfr[kk][i] = *(const bf16x8*)&Bs[cb + kk * 4096 + (wn * 64 + i * 16 + l15) * 32 + l4 * 8];
            }
        }

        // 3. MFMA cluster (hides the in-flight loads)
        __builtin_amdgcn_s_setprio(1);
#pragma unroll
        for (int kk = 0; kk < 2; kk++)
#pragma unroll
            for (int i = 0; i < 4; i++)
#pragma unroll
                for (int j = 0; j < 4; j++)
                    acc[i][j] = MFMA16(af[kk][i], bfr[kk][j], acc[i][j]);
        __builtin_amdgcn_s_setprio(0);

        // 4. AF32: convert prefetched A and write to the other buffer
        if (AF32 && more) {
#pragma unroll
            for (int i = 0; i < 4; i++) {
                bf16x8 v;
#pragma unroll
                for (int e = 0; e < 4; e++) {
                    v[e]     = (bf16_t)pf0[i][e];
                    v[e + 4] = (bf16_t)pf1[i][e];
                }
                *(bf16x8*)&As[nxt + eo[i]] = v;
            }
        }

        // 5. single barrier: drains gload_lds (vmcnt) + ds_writes (lgkm);
        //    also guarantees everyone finished reading buf cur.
        __syncthreads();
        cur ^= 1;
    }

    // epilogue: C/D layout col=lane&15, row=(lane>>4)*4+reg
#pragma unroll
    for (int i = 0; i < 4; i++)
#pragma unroll
        for (int j = 0; j < 4; j++)
#pragma unroll
            for (int r = 0; r < 4; r++) {
                int row = m0 + wm * 64 + i * 16 + l4 * 4 + r;
                int col = n0 + wn * 64 + j * 16 + l15;
                if (row < M) {
                    if (CF32) ((float*)Cv)[(size_t)row * N + col] = acc[i][j][r];
                    else ((bf16_t*)Cv)[(size_t)row * N + col] = (bf16_t)acc[i][j][r];
                }
            }
}

// ---------------------------------------------------------------------------
// prep: KV-proj from fp32 (blocks 0..79) + wq cvt (80..207) + wo cvt (208..335)
// KV GEMM: C[1232,1024] = cond[1232,768] @ [Wk|Wv][1024,768]^T, bf16 out,
// interleaved row stride 1024. (unchanged — small, ~10us)
// ---------------------------------------------------------------------------
__global__ __launch_bounds__(256) void prep(
    const float* __restrict__ cond, const float* __restrict__ w_k,
    const float* __restrict__ w_v, const float* __restrict__ w_q,
    const float* __restrict__ w_o, bf16_t* __restrict__ KVb,
    bf16_t* __restrict__ Wqb, bf16_t* __restrict__ Wob)
{
    __shared__ bf16_t As[2 * 128 * 32];
    __shared__ bf16_t Bs[2 * 128 * 32];

    const int bid = blockIdx.x;
    const int t = threadIdx.x;

    if (bid >= 80) {
        if (bid < 208) cvt8(w_q, Wqb, (long long)(bid - 80) * 256 + t);
        else           cvt8(w_o, Wob, (long long)(bid - 208) * 256 + t);
        return;
    }

    const int l = t & 63;
    const int w = t >> 6;
    const int wm = w >> 1, wn = w & 1;
    const int l15 = l & 15, l4 = l >> 4;
    const int m0 = (bid >> 3) * 128, n0 = (bid & 7) * 128;
    const int M = 1232, K = 768;

    floatx4 acc[4][4] = {};

    const float* ag[4];
    const float* bg[4];
    bf16_t* al[4];
    bf16_t* bl[4];
#pragma unroll
    for (int i = 0; i < 4; i++) {
        int e = (i * 256 + t) * 8;
        int kk = e >> 12;
        int row = (e & 4095) >> 5;
        int col = kk * 32 + (e & 31);
        int ra = m0 + row; if (ra > M - 1) ra = M - 1;
        ag[i] = cond + (size_t)ra * K + col;
        int rb = n0 + row;
        bg[i] = (rb < 512 ? w_k + (size_t)rb * K
                          : w_v + (size_t)(rb - 512) * K) + col;
        al[i] = &As[e];
        bl[i] = &Bs[e];
    }

    for (int k0 = 0; k0 < 768; k0 += 64) {
#pragma unroll
        for (int i = 0; i < 4; i++) {
            stage_cvt8(ag[i] + k0, al[i]);
            stage_cvt8(bg[i] + k0, bl[i]);
        }
        __syncthreads();

#pragma unroll
        for (int kk = 0; kk < 2; kk++) {
            bf16x8 af[4], bfr[4];
#pragma unroll
            for (int i = 0; i < 4; i++)
                af[i] = *(const bf16x8*)&As[kk * 4096 + (wm * 64 + i * 16 + l15) * 32 + l4 * 8];
#pragma unroll
            for (int j = 0; j < 4; j++)
                bfr[j] = *(const bf16x8*)&Bs[kk * 4096 + (wn * 64 + j * 16 + l15) * 32 + l4 * 8];
#pragma unroll
            for (int i = 0; i < 4; i++)
#pragma unroll
                for (int j = 0; j < 4; j++)
                    acc[i][j] = MFMA16(af[i], bfr[j], acc[i][j]);
        }
        __syncthreads();
    }

#pragma unroll
    for (int i = 0; i < 4; i++)
#pragma unroll
        for (int j = 0; j < 4; j++)
#pragma unroll
            for (int r = 0; r < 4; r++) {
                int row = m0 + wm * 64 + i * 16 + l4 * 4 + r;
                int col = n0 + wn * 64 + j * 16 + l15;
                if (row < M)
                    KVb[(size_t)row * 1024 + col] = (bf16_t)acc[i][j][r];
            }
}

// ---------------------------------------------------------------------------
// Fused attention, IN-PLACE on QO. 128 q-rows/block, 32 rows/wave.
// K/V interleaved: row j = [K(512) | V(512)], stride 1024.  (unchanged)
// grid: (Lq/128, B*H), block 256.
// ---------------------------------------------------------------------------
#define LK 77
#define KVSTR 1024
#define KSTR 72
#define VSTR 104
#define JP 96

__global__ __launch_bounds__(256) void attn_fused(
    bf16_t* QO,
    const bf16_t* __restrict__ KVg)
{
    __shared__ bf16_t Ks[80 * KSTR];
    __shared__ bf16_t Vs[64 * VSTR];
    __shared__ bf16_t Ps[4 * 32 * VSTR];

    const int t = threadIdx.x;
    const int w = t >> 6, l = t & 63;
    const int l15 = l & 15, l4 = l >> 4;
    const int b = blockIdx.y >> 3, h = blockIdx.y & 7;
    const int q0 = blockIdx.x * 128;

    const bf16_t* qbase =
        QO + ((size_t)(b * 4096 + q0 + w * 32 + l15)) * 512 + h * 64 + l4 * 8;
    bf16x8 aq[2][2];
    aq[0][0] = *(const bf16x8*)qbase;
    aq[0][1] = *(const bf16x8*)(qbase + 32);
    aq[1][0] = *(const bf16x8*)(qbase + 16 * 512);
    aq[1][1] = *(const bf16x8*)(qbase + 16 * 512 + 32);

    const bf16_t* Kg = KVg;
    const bf16_t* Vg = KVg + 512;

    for (int idx = t; idx < LK * 8; idx += 256) {
        int j = idx >> 3, c = (idx & 7) * 8;
        *(uint4*)&Ks[j * KSTR + c] =
            *(const uint4*)&Kg[((size_t)(b * LK + j)) * KVSTR + h * 64 + c];
    }
    for (int idx = t; idx < 3 * KSTR; idx += 256)
        Ks[LK * KSTR + idx] = (bf16_t)0.0f;

    for (int u = t; u < LK * 8; u += 256) {
        int j = u >> 3, d0 = (u & 7) * 8;
        uint4 pk = *(const uint4*)&Vg[((size_t)(b * LK + j)) * KVSTR + h * 64 + d0];
        const bf16_t* pv = (const bf16_t*)&pk;
#pragma unroll
        for (int e = 0; e < 8; e++)
            Vs[(d0 + e) * VSTR + j] = pv[e];
    }
    for (int idx = t; idx < 64 * (JP - LK); idx += 256) {
        int d = idx / (JP - LK), j = LK + idx % (JP - LK);
        Vs[d * VSTR + j] = (bf16_t)0.0f;
    }
    __syncthreads();

    floatx4 s[2][5];
    __builtin_amdgcn_s_setprio(1);
#pragma unroll
    for (int n = 0; n < 5; n++) {
        bf16x8 b0 = *(const bf16x8*)&Ks[(n * 16 + l15) * KSTR + l4 * 8];
        bf16x8 b1 = *(const bf16x8*)&Ks[(n * 16 + l15) * KSTR + 32 + l4 * 8];
#pragma unroll
        for (int mi = 0; mi < 2; mi++) {
            floatx4 z = {0.f, 0.f, 0.f, 0.f};
            z = MFMA16(aq[mi][0], b0, z);
            z = MFMA16(aq[mi][1], b1, z);
            s[mi][n] = z;
        }
    }
    __builtin_amdgcn_s_setprio(0);

    const float scale = 0.125f;
    float p[2][5][4], linv[2][4];
#pragma unroll
    for (int mi = 0; mi < 2; mi++)
#pragma unroll
        for (int r = 0; r < 4; r++) {
            float smax = -1e30f;
#pragma unroll
            for (int n = 0; n < 5; n++) {
                float v = s[mi][n][r] * scale;
                if (n == 4 && (64 + l15) >= LK) v = -1e30f;
                p[mi][n][r] = v;
                smax = fmaxf(smax, v);
            }
#pragma unroll
            for (int off = 1; off < 16; off <<= 1)
                smax = fmaxf(smax, __shfl_xor(smax, off, 64));
            float sum = 0.f;
#pragma unroll
            for (int n = 0; n < 5; n++) {
                float e2 = __expf(p[mi][n][r] - smax);
                p[mi][n][r] = e2;
                sum += e2;
            }
#pragma unroll
            for (int off = 1; off < 16; off <<= 1)
                sum += __shfl_xor(sum, off, 64);
            linv[mi][r] = 1.0f / sum;
        }

    bf16_t* pw = Ps + w * 32 * VSTR;
#pragma unroll
    for (int mi = 0; mi < 2; mi++)
#pragma unroll
        for (int r = 0; r < 4; r++) {
            int row = mi * 16 + l4 * 4 + r;
#pragma unroll
            for (int n = 0; n < 5; n++)
                pw[row * VSTR + n * 16 + l15] = (bf16_t)(p[mi][n][r] * linv[mi][r]);
            pw[row * VSTR + 80 + l15] = (bf16_t)0.0f;
        }
    __syncthreads();

    bf16x8 ap[2][3];
#pragma unroll
    for (int mi = 0; mi < 2; mi++)
#pragma unroll
        for (int ks = 0; ks < 3; ks++)
            ap[mi][ks] = *(const bf16x8*)&pw[(mi * 16 + l15) * VSTR + ks * 32 + l4 * 8];
#pragma unroll
    for (int n2 = 0; n2 < 4; n2++) {
        bf16x8 bv[3];
#pragma unroll
        for (int ks = 0; ks < 3; ks++)
            bv[ks] = *(const bf16x8*)&Vs[(n2 * 16 + l15) * VSTR + ks * 32 + l4 * 8];
        floatx4 o[2];
        __builtin_amdgcn_s_setprio(1);
#pragma unroll
        for (int mi = 0; mi < 2; mi++) {
            floatx4 z = {0.f, 0.f, 0.f, 0.f};
#pragma unroll
            for (int ks = 0; ks < 3; ks++)
                z = MFMA16(ap[mi][ks], bv[ks], z);
            o[mi] = z;
        }
        __builtin_amdgcn_s_setprio(0);
#pragma unroll
        for (int mi = 0; mi < 2; mi++)
#pragma unroll
            for (int r = 0; r < 4; r++) {
                int q = q0 + w * 32 + mi * 16 + l4 * 4 + r;
                QO[((size_t)(b * 4096 + q)) * 512 + h * 64 + n2 * 16 + l15] =
                    (bf16_t)o[mi][r];
            }
    }
}

// ---------------------------------------------------------------------------
extern "C" void kernel_launch(void* const* d_in, const int* in_sizes, int n_in,
                              void* d_out, int out_size, void* d_ws, size_t ws_size,
                              hipStream_t stream)
{
    const float* x    = (const float*)d_in[0];  // [16,4096,512] fp32
    const float* cond = (const float*)d_in[1];  // [16,77,768]   fp32
    const float* w_q  = (const float*)d_in[2];  // [512,512]     fp32
    const float* w_k  = (const float*)d_in[3];  // [512,768]     fp32
    const float* w_v  = (const float*)d_in[4];  // [512,768]     fp32
    const float* w_o  = (const float*)d_in[5];  // [512,512]     fp32
    float* out = (float*)d_out;                 // [16,4096,512] fp32

    const int Mq  = 16 * 4096;   // 65536
    const int Mkv = 16 * 77;     // 1232

    // workspace (bf16): Q/AO 67.1MB | KV 2.5MB | Wq 0.5MB | Wo 0.5MB ≈ 70.6MB
    bf16_t* Qb  = (bf16_t*)d_ws;
    bf16_t* KVb = Qb  + (size_t)Mq * 512;
    bf16_t* Wqb = KVb + (size_t)Mkv * 1024;
    bf16_t* Wob = Wqb + (size_t)512 * 512;

    // 1. prep: KV-proj from fp32 + wq/wo conversion (one launch)
    prep<<<dim3(336), 256, 0, stream>>>(cond, w_k, w_v, w_q, w_o, KVb, Wqb, Wob);

    // 2. Q-projection: A = x fp32 (reg-prefetch pipeline), B = Wqb
    gemm_bt<true, false><<<dim3(4, Mq / 128), 256, 0, stream>>>(x, Wqb, Qb, Mq, 512, 512);

    // 3. fused attention (Q -> AO in place)
    attn_fused<<<dim3(32, 128), 256, 0, stream>>>(Qb, KVb);

    // 4. O-projection: A = Qb bf16 (dbuf gload_lds pipeline), C = out fp32
    gemm_bt<false, true><<<dim3(4, Mq / 128), 256, 0, stream>>>(Qb, Wob, out, Mq, 512, 512);
}